// Round 13
// baseline (154.164 us; speedup 1.0000x reference)
//
#include <hip/hip_runtime.h>

// out[n,k] = sum_{i,j} x[n,i] * W[k,i,j] * x[n,j]   (N=262144 rows, D=32)
// R13 = R12 (best, 30.1us) + VISIBILITY PROBE: a uniform ~20us SALU spin
// (runtime-bounded s_nop loop) at kernel start. Purpose: since R4 the kernel
// has been faster than the harness's 268MB poison fills (~40us) and thus
// absent from the top-5 rocprof rows - no counters for any plateau variant.
// The spin shifts every wave equally (no regs touched, no memory), pushing
// dur to ~50us so the top-5 rows become OUR kernel with representative
// counters: VGPR_Count (spill check), WRITE_SIZE (33.5MB ideal), FETCH_SIZE
// (x L3-residency), MfmaUtil/VALUBusy (us per pipe), OccupancyPercent.
// dur_us this round is sacrificial (+~20us by construction).
//
// Algorithm (R12, verified absmax 0.25): symmetrized circular-diagonal GEMM,
// K = 528 = 33 MFMA steps of v_mfma_f32_32x32x16_f16; one-time prep kernel
// builds the f16 Wsym fragment table in d_ws; main kernel copies it to LDS
// (coalesced), packs 2 rows/lane to f16 pairs, SSA-pure K-loop.

typedef _Float16 f16x2 __attribute__((ext_vector_type(2)));
typedef _Float16 f16x4 __attribute__((ext_vector_type(4)));
typedef _Float16 f16x8 __attribute__((ext_vector_type(8)));
typedef float    f32x16 __attribute__((ext_vector_type(16)));

static __device__ __forceinline__ unsigned int pk2_f16(float lo, float hi) {
    return __builtin_bit_cast(unsigned int, __builtin_amdgcn_cvt_pkrtz(lo, hi));
}
static __device__ __forceinline__ f16x2 u2h(unsigned int u) {
    return __builtin_bit_cast(f16x2, u);
}
static __device__ __forceinline__ unsigned short f16b(float f) {
    _Float16 h = (_Float16)f;
    return __builtin_bit_cast(unsigned short, h);
}

// ---- one-time prep: symmetrized fragment table (16896 f16 = 33 KiB) ----
__global__ __launch_bounds__(512)
void prep_btab_sym(const float* __restrict__ W, unsigned short* __restrict__ bt) {
    int idx = blockIdx.x * 512 + threadIdx.x;   // 0..16895 (grid = 33)
    int n = idx >> 9;
    int e = idx & 511;
    int l = e >> 3, b = e & 7;
    int d = (n == 32) ? 16 : (n >> 1);
    int q = (n == 32) ? 0  : (n & 1);
    int i = q * 16 + ((l >> 5) << 3) + b;
    int j = (i + d) & 31;
    const float* Wk = W + (l & 31) * 1024;
    float v = (d == 0) ? Wk[i * 32 + i] : Wk[i * 32 + j] + Wk[j * 32 + i];
    bt[idx] = f16b(v);
}

__global__ __launch_bounds__(512, 2)
void quadform_kernel(const float* __restrict__ x,
                     const unsigned short* __restrict__ bt_ws,
                     float* __restrict__ out,
                     int delay) {
    // ---- visibility spin: pure SALU, uniform across all waves ----
    for (int t = 0; t < delay; ++t)
        asm volatile("s_nop 7");

    __shared__ __align__(16) unsigned short btab[33 * 64 * 8];   // 33 KiB

    const int tid  = threadIdx.x;
    const int lane = tid & 63;
    const int wave = tid >> 6;
    const int hi   = lane >> 5;
    const int rl   = lane & 31;
    const long rowbase = (long)blockIdx.x * 512 + wave * 64;

    const float4* xr0 = (const float4*)(x + (rowbase + rl) * 32);
    const float4* xr1 = (const float4*)(x + (rowbase + 32 + rl) * 32);

    // ---- coalesced copy ws -> LDS (2112 uint4) ----
    {
        const uint4* src = (const uint4*)bt_ws;
        uint4* dst = (uint4*)btab;
        #pragma unroll
        for (int c = 0; c < 5; ++c) {
            int idx = c * 512 + tid;
            if (idx < 2112) dst[idx] = src[idx];
        }
    }

    // ---- pack rows to f16 pairs, pre-rotate by hi*4 (static indices) ----
    unsigned int ypk0[16], ypk1[16];
    {
        unsigned int xpk0[16], xpk1[16];
        #pragma unroll
        for (int c = 0; c < 8; ++c) {
            float4 v0 = xr0[c];
            float4 v1 = xr1[c];
            xpk0[2 * c + 0] = pk2_f16(v0.x, v0.y);
            xpk0[2 * c + 1] = pk2_f16(v0.z, v0.w);
            xpk1[2 * c + 0] = pk2_f16(v1.x, v1.y);
            xpk1[2 * c + 1] = pk2_f16(v1.z, v1.w);
        }
        #pragma unroll
        for (int c = 0; c < 16; ++c) {
            ypk0[c] = hi ? xpk0[(c + 4) & 15] : xpk0[c];
            ypk1[c] = hi ? xpk1[(c + 4) & 15] : xpk1[c];
        }
    }

    f32x16 accA, accB;
    #pragma unroll
    for (int e = 0; e < 16; ++e) { accA[e] = 0.0f; accB[e] = 0.0f; }

    __syncthreads();

    // ---- K loop: 33 steps (17 circular diagonals), fully unrolled, SSA ----
    #pragma unroll
    for (int s = 0; s < 33; ++s) {
        const int d   = (s == 32) ? 16 : (s >> 1);
        const int q8  = ((s == 32) ? 0 : (s & 1)) * 8;
        const int dh  = d >> 1;
        const bool od = (d & 1) != 0;
        f16x8 bfrag = *(const f16x8*)(&btab[(s * 64 + lane) * 8]);

        {   // tile 0
            f16x2 b0 = od ? u2h(__builtin_amdgcn_perm(ypk0[(q8 + 0 + dh + 1) & 15], ypk0[(q8 + 0 + dh) & 15], 0x05040302u)) : u2h(ypk0[(q8 + 0 + dh) & 15]);
            f16x2 b1 = od ? u2h(__builtin_amdgcn_perm(ypk0[(q8 + 1 + dh + 1) & 15], ypk0[(q8 + 1 + dh) & 15], 0x05040302u)) : u2h(ypk0[(q8 + 1 + dh) & 15]);
            f16x2 b2 = od ? u2h(__builtin_amdgcn_perm(ypk0[(q8 + 2 + dh + 1) & 15], ypk0[(q8 + 2 + dh) & 15], 0x05040302u)) : u2h(ypk0[(q8 + 2 + dh) & 15]);
            f16x2 b3 = od ? u2h(__builtin_amdgcn_perm(ypk0[(q8 + 3 + dh + 1) & 15], ypk0[(q8 + 3 + dh) & 15], 0x05040302u)) : u2h(ypk0[(q8 + 3 + dh) & 15]);
            f16x2 a0 = u2h(ypk0[q8 + 0]) * b0;
            f16x2 a1 = u2h(ypk0[q8 + 1]) * b1;
            f16x2 a2 = u2h(ypk0[q8 + 2]) * b2;
            f16x2 a3 = u2h(ypk0[q8 + 3]) * b3;
            f16x4 lo = __builtin_shufflevector(a0, a1, 0, 1, 2, 3);
            f16x4 hf = __builtin_shufflevector(a2, a3, 0, 1, 2, 3);
            f16x8 a  = __builtin_shufflevector(lo, hf, 0, 1, 2, 3, 4, 5, 6, 7);
            accA = __builtin_amdgcn_mfma_f32_32x32x16_f16(a, bfrag, accA, 0, 0, 0);
        }
        {   // tile 1
            f16x2 b0 = od ? u2h(__builtin_amdgcn_perm(ypk1[(q8 + 0 + dh + 1) & 15], ypk1[(q8 + 0 + dh) & 15], 0x05040302u)) : u2h(ypk1[(q8 + 0 + dh) & 15]);
            f16x2 b1 = od ? u2h(__builtin_amdgcn_perm(ypk1[(q8 + 1 + dh + 1) & 15], ypk1[(q8 + 1 + dh) & 15], 0x05040302u)) : u2h(ypk1[(q8 + 1 + dh) & 15]);
            f16x2 b2 = od ? u2h(__builtin_amdgcn_perm(ypk1[(q8 + 2 + dh + 1) & 15], ypk1[(q8 + 2 + dh) & 15], 0x05040302u)) : u2h(ypk1[(q8 + 2 + dh) & 15]);
            f16x2 b3 = od ? u2h(__builtin_amdgcn_perm(ypk1[(q8 + 3 + dh + 1) & 15], ypk1[(q8 + 3 + dh) & 15], 0x05040302u)) : u2h(ypk1[(q8 + 3 + dh) & 15]);
            f16x2 a0 = u2h(ypk1[q8 + 0]) * b0;
            f16x2 a1 = u2h(ypk1[q8 + 1]) * b1;
            f16x2 a2 = u2h(ypk1[q8 + 2]) * b2;
            f16x2 a3 = u2h(ypk1[q8 + 3]) * b3;
            f16x4 lo = __builtin_shufflevector(a0, a1, 0, 1, 2, 3);
            f16x4 hf = __builtin_shufflevector(a2, a3, 0, 1, 2, 3);
            f16x8 a  = __builtin_shufflevector(lo, hf, 0, 1, 2, 3, 4, 5, 6, 7);
            accB = __builtin_amdgcn_mfma_f32_32x32x16_f16(a, bfrag, accB, 0, 0, 0);
        }
    }

    // ---- store: col = lane&31 (k), row = (e&3) + 8*(e>>2) + 4*hi ----
    #pragma unroll
    for (int e = 0; e < 16; ++e) {
        int row = (e & 3) + 8 * (e >> 2) + 4 * hi;
        out[(rowbase + row) * 32 + rl]      = accA[e];
        out[(rowbase + 32 + row) * 32 + rl] = accB[e];
    }
}

extern "C" void kernel_launch(void* const* d_in, const int* in_sizes, int n_in,
                              void* d_out, int out_size, void* d_ws, size_t ws_size,
                              hipStream_t stream) {
    const float* x = (const float*)d_in[0];
    const float* W = (const float*)d_in[1];
    float* out = (float*)d_out;
    unsigned short* bt = (unsigned short*)d_ws;    // 33 KiB table

    prep_btab_sym<<<33, 512, 0, stream>>>(W, bt);
    int nrows = in_sizes[0] / 32;          // 262144
    int grid  = nrows / 512;               // 512 blocks x 512 thr
    quadform_kernel<<<grid, 512, 0, stream>>>(x, bt, out, 4000);
}

// Round 14
// 27.150 us; speedup vs baseline: 5.6783x; 5.6783x over previous
//
#include <hip/hip_runtime.h>

// out[n,k] = sum_{i,j} x[n,i] * W[k,i,j] * x[n,j]   (N=262144 rows, D=32)
// R14 vs R12 (30.1us): OCCUPANCY. R13's spin-probe counters for the R12
// structure: WRITE=32.8MB (ideal, no spill), FETCH=16.7MB, bank conflicts 0,
// MFMA busy 3.4us, VALU busy 8.0us, BW 21% peak, Occupancy 42.6% -- the
// classic latency-bound quadrant. Limiter = 116 live regs (ypk 32 + acc 32
// + temps) -> 16 waves/CU. Fix: ONE 32-row tile per wave (state: ypk 16 +
// acc 16 + temps ~= 60 regs), launch_bounds(512,6) (cap 85, zero spill
// margin risk) -> 3 blocks/CU x 8 waves = 24 waves/CU (75%), 8192 waves
// total (2x) with natural cross-generation phase stagger.
// Cost: bfrag ds_reads double (each wave reads the whole 33KiB table);
// hidden by the added TLP. K-loop math identical to R12 (absmax 0.25).
//
// Algorithm: symmetrized circular-diagonal GEMM. p = d*32+i, d=0..16,
// z[n,p] = x[n,i]*x[n,(i+d)&31], Wf[p,k] = W[k,i,j]+W[k,j,i] (d=0 diag,
// d=16 half), K = 528 = 33 MFMA steps of v_mfma_f32_32x32x16_f16.
// One-time prep kernel builds the f16 Wsym fragment table in d_ws.

typedef _Float16 f16x2 __attribute__((ext_vector_type(2)));
typedef _Float16 f16x4 __attribute__((ext_vector_type(4)));
typedef _Float16 f16x8 __attribute__((ext_vector_type(8)));
typedef float    f32x16 __attribute__((ext_vector_type(16)));

static __device__ __forceinline__ unsigned int pk2_f16(float lo, float hi) {
    return __builtin_bit_cast(unsigned int, __builtin_amdgcn_cvt_pkrtz(lo, hi));
}
static __device__ __forceinline__ f16x2 u2h(unsigned int u) {
    return __builtin_bit_cast(f16x2, u);
}
static __device__ __forceinline__ unsigned short f16b(float f) {
    _Float16 h = (_Float16)f;
    return __builtin_bit_cast(unsigned short, h);
}

// ---- one-time prep: symmetrized fragment table (16896 f16 = 33 KiB) ----
// bt[(n*64+l)*8+b] = f16( W[k,i,j]+W[k,j,i] ),  k=l&31, i=q*16+(l>>5)*8+b,
// j=(i+d)&31, d=(n==32)?16:n>>1, q=(n==32)?0:n&1;  d==0 -> W[k,i,i].
__global__ __launch_bounds__(512)
void prep_btab_sym(const float* __restrict__ W, unsigned short* __restrict__ bt) {
    int idx = blockIdx.x * 512 + threadIdx.x;   // 0..16895 (grid = 33)
    int n = idx >> 9;
    int e = idx & 511;
    int l = e >> 3, b = e & 7;
    int d = (n == 32) ? 16 : (n >> 1);
    int q = (n == 32) ? 0  : (n & 1);
    int i = q * 16 + ((l >> 5) << 3) + b;
    int j = (i + d) & 31;
    const float* Wk = W + (l & 31) * 1024;
    float v = (d == 0) ? Wk[i * 32 + i] : Wk[i * 32 + j] + Wk[j * 32 + i];
    bt[idx] = f16b(v);
}

__global__ __launch_bounds__(512, 6)
void quadform_kernel(const float* __restrict__ x,
                     const unsigned short* __restrict__ bt_ws,
                     float* __restrict__ out) {
    __shared__ __align__(16) unsigned short btab[33 * 64 * 8];   // 33 KiB

    const int tid  = threadIdx.x;
    const int lane = tid & 63;
    const int wave = tid >> 6;
    const int hi   = lane >> 5;
    const int rl   = lane & 31;
    const long wrow = (long)blockIdx.x * 256 + wave * 32;   // 1 tile (32 rows)/wave

    // ---- x row load issued first (hides under btab copy) ----
    const float4* xr = (const float4*)(x + (wrow + rl) * 32);

    // ---- coalesced copy ws -> LDS (2112 uint4) ----
    {
        const uint4* src = (const uint4*)bt_ws;
        uint4* dst = (uint4*)btab;
        #pragma unroll
        for (int c = 0; c < 5; ++c) {
            int idx = c * 512 + tid;
            if (idx < 2112) dst[idx] = src[idx];
        }
    }

    // ---- pack row to f16 pairs, pre-rotate by hi*4 (static indices) ----
    unsigned int ypk[16];
    {
        unsigned int xpk[16];
        #pragma unroll
        for (int c = 0; c < 8; ++c) {
            float4 v = xr[c];
            xpk[2 * c + 0] = pk2_f16(v.x, v.y);
            xpk[2 * c + 1] = pk2_f16(v.z, v.w);
        }
        #pragma unroll
        for (int c = 0; c < 16; ++c)
            ypk[c] = hi ? xpk[(c + 4) & 15] : xpk[c];
    }

    f32x16 acc;
    #pragma unroll
    for (int e = 0; e < 16; ++e) acc[e] = 0.0f;

    __syncthreads();

    // ---- K loop: 33 steps (17 circular diagonals), fully unrolled, SSA ----
    #pragma unroll
    for (int s = 0; s < 33; ++s) {
        const int d   = (s == 32) ? 16 : (s >> 1);
        const int q8  = ((s == 32) ? 0 : (s & 1)) * 8;
        const int dh  = d >> 1;
        const bool od = (d & 1) != 0;
        f16x8 bfrag = *(const f16x8*)(&btab[(s * 64 + lane) * 8]);

        f16x2 b0 = od ? u2h(__builtin_amdgcn_perm(ypk[(q8 + 0 + dh + 1) & 15], ypk[(q8 + 0 + dh) & 15], 0x05040302u)) : u2h(ypk[(q8 + 0 + dh) & 15]);
        f16x2 b1 = od ? u2h(__builtin_amdgcn_perm(ypk[(q8 + 1 + dh + 1) & 15], ypk[(q8 + 1 + dh) & 15], 0x05040302u)) : u2h(ypk[(q8 + 1 + dh) & 15]);
        f16x2 b2 = od ? u2h(__builtin_amdgcn_perm(ypk[(q8 + 2 + dh + 1) & 15], ypk[(q8 + 2 + dh) & 15], 0x05040302u)) : u2h(ypk[(q8 + 2 + dh) & 15]);
        f16x2 b3 = od ? u2h(__builtin_amdgcn_perm(ypk[(q8 + 3 + dh + 1) & 15], ypk[(q8 + 3 + dh) & 15], 0x05040302u)) : u2h(ypk[(q8 + 3 + dh) & 15]);
        f16x2 a0 = u2h(ypk[q8 + 0]) * b0;
        f16x2 a1 = u2h(ypk[q8 + 1]) * b1;
        f16x2 a2 = u2h(ypk[q8 + 2]) * b2;
        f16x2 a3 = u2h(ypk[q8 + 3]) * b3;
        f16x4 lo = __builtin_shufflevector(a0, a1, 0, 1, 2, 3);
        f16x4 hf = __builtin_shufflevector(a2, a3, 0, 1, 2, 3);
        f16x8 a  = __builtin_shufflevector(lo, hf, 0, 1, 2, 3, 4, 5, 6, 7);
        acc = __builtin_amdgcn_mfma_f32_32x32x16_f16(a, bfrag, acc, 0, 0, 0);
    }

    // ---- store: col = lane&31 (k), row = (e&3) + 8*(e>>2) + 4*hi ----
    #pragma unroll
    for (int e = 0; e < 16; ++e) {
        int row = (e & 3) + 8 * (e >> 2) + 4 * hi;
        out[(wrow + row) * 32 + rl] = acc[e];
    }
}

extern "C" void kernel_launch(void* const* d_in, const int* in_sizes, int n_in,
                              void* d_out, int out_size, void* d_ws, size_t ws_size,
                              hipStream_t stream) {
    const float* x = (const float*)d_in[0];
    const float* W = (const float*)d_in[1];
    float* out = (float*)d_out;
    unsigned short* bt = (unsigned short*)d_ws;    // 33 KiB table

    prep_btab_sym<<<33, 512, 0, stream>>>(W, bt);
    int nrows = in_sizes[0] / 32;          // 262144
    int grid  = nrows / 256;               // 1024 blocks x 512 thr (1 tile/wave)
    quadform_kernel<<<grid, 512, 0, stream>>>(x, bt, out);
}